// Round 1
// baseline (31.604 us; speedup 1.0000x reference)
//
#include <hip/hip_runtime.h>
#include <cfloat>
#include <climits>

#define TT 1024
#define BB 16
#define DD 512
#define VV 1000

// Kernel 1: one 64-lane wave per (t,b) position computes argmax over V logits.
// First-occurrence tie-break to match jnp.argmax exactly.
__global__ void argmax_kernel(const float* __restrict__ logit, int* __restrict__ labels) {
    int gw   = (blockIdx.x * blockDim.x + threadIdx.x) >> 6;   // global wave id = t*B + b
    int lane = threadIdx.x & 63;
    if (gw >= TT * BB) return;
    const float4* row = (const float4*)(logit + (size_t)gw * VV);  // 4000B rows, 16B aligned
    float best = -FLT_MAX;
    int   bidx = INT_MAX;
    for (int i = lane; i < VV / 4; i += 64) {           // 250 float4 per row
        float4 v = row[i];
        int base = i * 4;
        // within-lane indices ascend, so strict > keeps the earliest index
        if (v.x > best) { best = v.x; bidx = base;     }
        if (v.y > best) { best = v.y; bidx = base + 1; }
        if (v.z > best) { best = v.z; bidx = base + 2; }
        if (v.w > best) { best = v.w; bidx = base + 3; }
    }
    // cross-lane reduce with index tie-break (lower index wins on equal value)
    for (int off = 32; off; off >>= 1) {
        float ov = __shfl_xor(best, off);
        int   oi = __shfl_xor(bidx, off);
        if (ov > best || (ov == best && oi < bidx)) { best = ov; bidx = oi; }
    }
    if (lane == 0) {
        int t = gw / BB, b = gw % BB;                   // logit layout is (T,B,V)
        labels[b * TT + t] = bidx;                      // store as (B,T)
    }
}

// Kernel 2: one 1024-thread block per batch. Inclusive scan of change flags ->
// seg ids; LDS counts -> per-timestep weight 1/runlen; seg starts; new padding.
__global__ void seg_kernel(const int* __restrict__ labels,
                           const unsigned char* __restrict__ padding,
                           float* __restrict__ w, int* __restrict__ seg_start,
                           int* __restrict__ nseg, float* __restrict__ out_pad) {
    int b = blockIdx.x;
    int t = threadIdx.x;                 // 0..1023
    int lane = t & 63, wid = t >> 6;
    __shared__ int wsum[16];
    __shared__ int cnt[TT];

    int lab   = labels[b * TT + t];
    int prev  = (t > 0) ? labels[b * TT + t - 1] : -1;   // shifted label, -1 at t=0
    int valid = padding[b * TT + t] ? 0 : 1;
    int change = (valid && lab != prev) ? 1 : 0;

    // wave-level inclusive scan
    int x = change;
    for (int off = 1; off < 64; off <<= 1) {
        int y = __shfl_up(x, off);
        if (lane >= off) x += y;
    }
    if (lane == 63) wsum[wid] = x;
    cnt[t] = 0;
    __syncthreads();
    if (t == 0) {                         // serial scan of 16 wave totals
        int acc = 0;
        for (int i = 0; i < 16; ++i) { acc += wsum[i]; wsum[i] = acc; }
    }
    __syncthreads();
    int incl = x + (wid > 0 ? wsum[wid - 1] : 0);  // cumsum(change)[t]
    int seg  = incl - 1;                            // seg_id per reference
    int ns   = wsum[15];                            // total segments this batch

    if (valid && seg >= 0) atomicAdd(&cnt[seg], 1);
    if (change) seg_start[b * TT + seg] = t;
    __syncthreads();

    w[b * TT + t] = (valid && seg >= 0) ? (1.0f / (float)cnt[seg]) : 0.0f;
    out_pad[b * TT + t] = (t >= ns) ? 1.0f : 0.0f;  // new_padding as 0/1 floats
    if (t == 0) nseg[b] = ns;
}

// Kernel 3: one 128-thread block per output row (s,b); each thread one float4
// of D=512. Gathers the weighted sum over the segment's time range.
__global__ void compress_kernel(const float* __restrict__ rep,
                                const float* __restrict__ w,
                                const int* __restrict__ seg_start,
                                const int* __restrict__ nseg,
                                float* __restrict__ out) {
    int b = blockIdx.x % BB;              // b fastest -> consecutive blocks write
    int s = blockIdx.x / BB;              // consecutive 2KB chunks
    int tid = threadIdx.x;                // 0..127
    int ns = nseg[b];
    float4 acc = make_float4(0.f, 0.f, 0.f, 0.f);
    if (s < ns) {
        int start = seg_start[b * TT + s];
        int end   = (s + 1 < ns) ? seg_start[b * TT + s + 1] : TT;
        for (int t = start; t < end; ++t) {
            float ww = w[b * TT + t];     // broadcast read
            if (ww != 0.0f) {             // skips invalid (padded) timesteps
                float4 r = ((const float4*)rep)[((size_t)t * BB + b) * (DD / 4) + tid];
                acc.x += ww * r.x; acc.y += ww * r.y;
                acc.z += ww * r.z; acc.w += ww * r.w;
            }
        }
    }
    ((float4*)out)[((size_t)s * BB + b) * (DD / 4) + tid] = acc;  // zeros past ns
}

extern "C" void kernel_launch(void* const* d_in, const int* in_sizes, int n_in,
                              void* d_out, int out_size, void* d_ws, size_t ws_size,
                              hipStream_t stream) {
    const float* rep            = (const float*)d_in[0];
    const float* logit          = (const float*)d_in[1];
    const unsigned char* paddng = (const unsigned char*)d_in[2];

    float* out     = (float*)d_out;
    float* out_pad = out + (size_t)TT * BB * DD;     // second output: (B,T) mask

    char* ws       = (char*)d_ws;
    int*   labels    = (int*)(ws);                   // B*T int   = 64 KiB
    float* w         = (float*)(ws + (1 << 16));     // B*T float = 64 KiB
    int*   seg_start = (int*)(ws + (2 << 16));       // B*T int   = 64 KiB
    int*   nseg      = (int*)(ws + (3 << 16));       // B int

    argmax_kernel  <<<(TT * BB) / 4, 256, 0, stream>>>(logit, labels);
    seg_kernel     <<<BB, TT, 0, stream>>>(labels, paddng, w, seg_start, nseg, out_pad);
    compress_kernel<<<BB * TT, 128, 0, stream>>>(rep, w, seg_start, nseg, out);
}